// Round 5
// baseline (58.563 us; speedup 1.0000x reference)
//
#include <hip/hip_runtime.h>
#include <math.h>

// Problem shape (fixed by harness reference)
#define B_SZ 32
#define NM   2048     // N == M == 2048
#define D_SZ 32

typedef __attribute__((ext_vector_type(8))) _Float16 h8;   // MFMA A/B frag: 8 f16 = 4 VGPRs
typedef __attribute__((ext_vector_type(4))) float f4;      // MFMA C/D frag

// ---------------------------------------------------------------------------
// Pack X (and Y) into MFMA-fragment-ready f16 layout + fused squared norms
// (verified: absmax 0.0 in rounds 2-4). Tile t = 16 consecutive rows of
// flattened [B*NM]; lane l holds row t*16+(l&15), k = {4g+j} U {16+4g+j}.
// ---------------------------------------------------------------------------
__global__ __launch_bounds__(256)
void pack_kernel(const float* __restrict__ srcX, const float* __restrict__ srcY,
                 h8* __restrict__ dstX, h8* __restrict__ dstY,
                 float* __restrict__ nrmX, float* __restrict__ nrmY)
{
    const int gid = blockIdx.x * 256 + threadIdx.x;   // one thread per (tile,lane)
    const float* src = blockIdx.y ? srcY : srcX;
    h8*          dst = blockIdx.y ? dstY : dstX;
    float*       nrm = blockIdx.y ? nrmY : nrmX;

    const int l   = gid & 63;
    const int t   = gid >> 6;
    const int row = t * 16 + (l & 15);
    const int k0  = (l >> 4) * 4;

    const float* p = src + (size_t)row * D_SZ;
    f4 v0 = *(const f4*)(p + k0);        // k = k0..k0+3
    f4 v1 = *(const f4*)(p + 16 + k0);   // k = 16+k0..16+k0+3

    h8 h;
    h[0] = (_Float16)v0[0]; h[1] = (_Float16)v0[1];
    h[2] = (_Float16)v0[2]; h[3] = (_Float16)v0[3];
    h[4] = (_Float16)v1[0]; h[5] = (_Float16)v1[1];
    h[6] = (_Float16)v1[2]; h[7] = (_Float16)v1[3];
    dst[gid] = h;

    float s = 0.f;
#pragma unroll
    for (int j = 0; j < 4; ++j) {
        s = fmaf(v0[j], v0[j], s);
        s = fmaf(v1[j], v1[j], s);
    }
    s += __shfl_xor(s, 16);
    s += __shfl_xor(s, 32);
    if (l < 16) nrm[row] = s;   // exact fp32 norms
}

// ---------------------------------------------------------------------------
// One directional pass. dir=0: rows=X, cols=Y (X_inf). dir=1: roles swapped.
// 1D grid, XCD-swizzled: physical blocks round-robin over 8 XCDs [m09], so
// logical = (phys%8)*(nwg/8) + phys/8 groups 8 consecutive logical blocks
// (= one (dir,half,b) group sharing a 64KB B-slice) onto one XCD; 16 groups
// (~3MB distinct packed data) per XCD fit the 4MB private L2.
// Block = 4 waves, each owning 64 rows (4 A-frags); ALL waves sweep the SAME
// B-tile stream (L1/L2-hit sharing), direct global loads, no LDS, no
// barriers, depth-1 pointer-bump prefetch. MFMA C-operand seeded with
// -0.5*qnorm[col]:   min_j d2[i,j] = pnorm[i] - 2*max_j(dot - 0.5*qnorm[j])
// End: shfl-max over 16 col-lanes, lc==0 lanes store rows directly (waves own
// disjoint rows). C/D layout (m89-verified): col=lane&15, row=(lane>>4)*4+reg.
// ---------------------------------------------------------------------------
#define PASS_BODY(BF, CV)                                                     \
    {                                                                         \
        const float ch_ = -0.5f * (CV);                                       \
        const f4 cs_ = {ch_, ch_, ch_, ch_};                                  \
        f4 q0 = __builtin_amdgcn_mfma_f32_16x16x32_f16(a0, (BF), cs_, 0,0,0); \
        f4 q1 = __builtin_amdgcn_mfma_f32_16x16x32_f16(a1, (BF), cs_, 0,0,0); \
        f4 q2 = __builtin_amdgcn_mfma_f32_16x16x32_f16(a2, (BF), cs_, 0,0,0); \
        f4 q3 = __builtin_amdgcn_mfma_f32_16x16x32_f16(a3, (BF), cs_, 0,0,0); \
        _Pragma("unroll")                                                     \
        for (int r = 0; r < 4; ++r) {                                         \
            mx0[r] = fmaxf(mx0[r], q0[r]);                                    \
            mx1[r] = fmaxf(mx1[r], q1[r]);                                    \
            mx2[r] = fmaxf(mx2[r], q2[r]);                                    \
            mx3[r] = fmaxf(mx3[r], q3[r]);                                    \
        }                                                                     \
    }

__global__ __launch_bounds__(256, 4)
void chamfer_pass(const h8* __restrict__ Xpk, const h8* __restrict__ Ypk,
                  const float* __restrict__ x2g, const float* __restrict__ y2g,
                  float* __restrict__ mp, int nh, int tph /* = 128/nh */)
{
    // XCD swizzle (nwg = 512 or 1024, both %8 == 0 -> bijective)
    const int nwg  = gridDim.x;
    const int phys = blockIdx.x;
    const int lg   = (phys & 7) * (nwg >> 3) + (phys >> 3);
    const int xb   = lg & 7;            // 8 row-blocks of 256
    const int rest = lg >> 3;
    const int b    = rest & 31;
    const int z    = rest >> 5;         // 0 .. 2*nh-1
    const int dir  = z / nh;
    const int half = z % nh;

    const int tid = threadIdx.x;
    const int w   = tid >> 6;
    const int l   = tid & 63;
    const int lc  = l & 15;
    const int g   = l >> 4;

    const h8* Ppk = dir ? Ypk : Xpk;
    const h8* Qpk = dir ? Xpk : Ypk;
    const float* qn = dir ? x2g : y2g;

    const int row0 = xb * 256 + w * 64;                   // within batch
    const size_t pt0 = ((size_t)b * NM + row0) >> 4;      // global 16-row tile
    const h8* pa = Ppk + pt0 * 64 + l;
    h8 a0 = pa[0], a1 = pa[64], a2 = pa[128], a3 = pa[192];

    const int mt0 = half * tph;
    const h8*    qb  = Qpk + ((size_t)b * (NM / 16) + mt0) * 64 + l;
    const float* qnb = qn + (size_t)b * NM + mt0 * 16 + lc;

    const float NEGINF = -3.0e38f;
    f4 mx0 = {NEGINF, NEGINF, NEGINF, NEGINF};
    f4 mx1 = mx0, mx2 = mx0, mx3 = mx0;

    h8 bf   = *qb;
    float c = *qnb;
    for (int t = 0; t < tph - 1; ++t) {
        qb += 64; qnb += 16;
        h8 nbf   = *qb;      // prefetch next tile (shared stream -> L1/L2 hit)
        float nc = *qnb;
        PASS_BODY(bf, c);
        bf = nbf; c = nc;
    }
    PASS_BODY(bf, c);        // peeled last tile

    // reduce max across the 16 column-lanes
#pragma unroll
    for (int m = 1; m <= 8; m <<= 1) {
#pragma unroll
        for (int r = 0; r < 4; ++r) {
            mx0[r] = fmaxf(mx0[r], __shfl_xor(mx0[r], m));
            mx1[r] = fmaxf(mx1[r], __shfl_xor(mx1[r], m));
            mx2[r] = fmaxf(mx2[r], __shfl_xor(mx2[r], m));
            mx3[r] = fmaxf(mx3[r], __shfl_xor(mx3[r], m));
        }
    }
    if (lc == 0) {   // 4 lanes per wave; rows row0 + i*16 + g*4 .. +3
        float* out = mp + ((size_t)(dir * nh + half) * B_SZ + b) * NM
                        + row0 + (g << 2);
        *(f4*)(out)      = mx0;
        *(f4*)(out + 16) = mx1;
        *(f4*)(out + 32) = mx2;
        *(f4*)(out + 48) = mx3;
    }
}

// ---------------------------------------------------------------------------
// Finalize: d2 = nrm - 2*max(halves), clamp, sqrt, deterministic tree sum.
// Exactly 32768 f4 elements -> grid 128 x 256, one f4 per thread.
// ---------------------------------------------------------------------------
__global__ __launch_bounds__(256)
void finalize1(const float* __restrict__ mp, const float* __restrict__ nrm,
               float* __restrict__ partials, int nh)
{
    const int i   = blockIdx.x * 256 + threadIdx.x;   // f4 index in [0, 32768)
    const int dir = i >> 14;
    const int r4  = i & 16383;
    const f4* n4 = (const f4*)(nrm + dir * 65536);
    const f4* m0 = (const f4*)(mp + (size_t)dir * nh * 65536);
    const f4* m1 = (const f4*)(mp + ((size_t)dir * nh + (nh - 1)) * 65536);
    f4 nv = n4[r4];
    f4 pa = m0[r4];
    f4 pb = m1[r4];   // nh==1: same as pa
    float s = 0.f;
#pragma unroll
    for (int r = 0; r < 4; ++r) {
        float d2 = fmaf(-2.f, fmaxf(pa[r], pb[r]), nv[r]);
        s += sqrtf(fmaxf(d2, 0.f));
    }
    __shared__ float wsum[4];
#pragma unroll
    for (int o = 32; o > 0; o >>= 1) s += __shfl_down(s, o, 64);
    if ((threadIdx.x & 63) == 0) wsum[threadIdx.x >> 6] = s;
    __syncthreads();
    if (threadIdx.x == 0)
        partials[blockIdx.x] = wsum[0] + wsum[1] + wsum[2] + wsum[3];
}

__global__ __launch_bounds__(64)
void finalize2(const float* __restrict__ partials, float* __restrict__ out, float scale)
{
    float s = partials[threadIdx.x] + partials[threadIdx.x + 64];
#pragma unroll
    for (int o = 32; o > 0; o >>= 1) s += __shfl_down(s, o, 64);
    if (threadIdx.x == 0) out[0] = s * scale;
}

extern "C" void kernel_launch(void* const* d_in, const int* in_sizes, int n_in,
                              void* d_out, int out_size, void* d_ws, size_t ws_size,
                              hipStream_t stream) {
    const float* X = (const float*)d_in[0];
    const float* Y = (const float*)d_in[1];

    // ws: mp nh*131072 f + partials 128 f + nrm 131072 f + packed 8.39 MB
    const int nh  = (ws_size >= 10100000u) ? 2 : 1;
    const int tph = 128 / nh;

    float* ws       = (float*)d_ws;
    float* mp       = ws;                              // nh*2*32*2048 floats
    float* partials = mp + (size_t)nh * 131072;        // 128 floats
    float* nrm      = partials + 128;                  // 131072 floats (x2 then y2)
    h8*    Xpk      = (h8*)(nrm + 131072);             // 262144 h8 (4.19 MB)
    h8*    Ypk      = Xpk + 262144;                    // 262144 h8 (4.19 MB)

    dim3 pgrid(1024, 2);
    pack_kernel<<<pgrid, 256, 0, stream>>>(X, Y, Xpk, Ypk, nrm, nrm + 65536);

    // 1D grid: 8 row-blocks x 32 batches x (2*nh) passes, XCD-swizzled inside
    chamfer_pass<<<8 * B_SZ * 2 * nh, 256, 0, stream>>>(Xpk, Ypk, nrm, nrm + 65536,
                                                        mp, nh, tph);

    finalize1<<<128, 256, 0, stream>>>(mp, nrm, partials, nh);
    finalize2<<<1, 64, 0, stream>>>(partials, (float*)d_out, 1.0f / 131072.0f);
}

// Round 6
// 36.636 us; speedup vs baseline: 1.5985x; 1.5985x over previous
//
#include <hip/hip_runtime.h>
#include <math.h>

// Problem shape (fixed by harness reference)
#define B_SZ 32
#define NM   2048     // N == M == 2048
#define D_SZ 32

typedef __attribute__((ext_vector_type(8))) _Float16 h8;   // MFMA A/B frag: 8 f16 = 4 VGPRs
typedef __attribute__((ext_vector_type(4))) float f4;      // MFMA C/D frag

// ---------------------------------------------------------------------------
// Pack X (and Y) into MFMA-fragment-ready f16 layout + fused squared norms
// (verified: absmax 0.0 in rounds 2-5). Tile t = 16 consecutive rows of
// flattened [B*NM]; lane l holds row t*16+(l&15), k = {4g+j} U {16+4g+j}.
// ---------------------------------------------------------------------------
__global__ __launch_bounds__(256)
void pack_kernel(const float* __restrict__ srcX, const float* __restrict__ srcY,
                 h8* __restrict__ dstX, h8* __restrict__ dstY,
                 float* __restrict__ nrmX, float* __restrict__ nrmY)
{
    const int gid = blockIdx.x * 256 + threadIdx.x;   // one thread per (tile,lane)
    const float* src = blockIdx.y ? srcY : srcX;
    h8*          dst = blockIdx.y ? dstY : dstX;
    float*       nrm = blockIdx.y ? nrmY : nrmX;

    const int l   = gid & 63;
    const int t   = gid >> 6;
    const int row = t * 16 + (l & 15);
    const int k0  = (l >> 4) * 4;

    const float* p = src + (size_t)row * D_SZ;
    f4 v0 = *(const f4*)(p + k0);        // k = k0..k0+3
    f4 v1 = *(const f4*)(p + 16 + k0);   // k = 16+k0..16+k0+3

    h8 h;
    h[0] = (_Float16)v0[0]; h[1] = (_Float16)v0[1];
    h[2] = (_Float16)v0[2]; h[3] = (_Float16)v0[3];
    h[4] = (_Float16)v1[0]; h[5] = (_Float16)v1[1];
    h[6] = (_Float16)v1[2]; h[7] = (_Float16)v1[3];
    dst[gid] = h;

    float s = 0.f;
#pragma unroll
    for (int j = 0; j < 4; ++j) {
        s = fmaf(v0[j], v0[j], s);
        s = fmaf(v1[j], v1[j], s);
    }
    s += __shfl_xor(s, 16);
    s += __shfl_xor(s, 32);
    if (l < 16) nrm[row] = s;   // exact fp32 norms
}

// ---------------------------------------------------------------------------
// One directional pass. dir=0: rows=X, cols=Y (X_inf). dir=1: roles swapped.
// 1D grid, XCD-swizzled (verified round 5: FETCH 37->12.6 MB): logical =
// (phys%8)*(nwg/8)+phys/8 groups the 8 row-blocks of one (dir,half,b) onto
// one XCD so its ~3MB working set fits the 4MB private L2.
// Block = 4 waves, each owning 64 rows (4 A-frags); ALL waves sweep the SAME
// B-tile stream. NEW (round 6): tile loop unrolled x4 with a 4-deep register
// prefetch batch — 4 independent B-frag + 4 norm loads in flight per wave
// while the previous 4 tiles compute (MLP 1 -> 4; the round-5 latency stall).
// MFMA C-operand seeded with -0.5*qnorm[col]:
//     min_j d2[i,j] = pnorm[i] - 2 * max_j (dot[i,j] - 0.5*qnorm[j])
// End: shfl-max over 16 col-lanes, lc==0 lanes store rows directly.
// C/D layout (m89-verified): col=lane&15, row=(lane>>4)*4+reg.
// ---------------------------------------------------------------------------
#define PASS_BODY(BF, CV)                                                     \
    {                                                                         \
        const float ch_ = -0.5f * (CV);                                       \
        const f4 cs_ = {ch_, ch_, ch_, ch_};                                  \
        f4 q0 = __builtin_amdgcn_mfma_f32_16x16x32_f16(a0, (BF), cs_, 0,0,0); \
        f4 q1 = __builtin_amdgcn_mfma_f32_16x16x32_f16(a1, (BF), cs_, 0,0,0); \
        f4 q2 = __builtin_amdgcn_mfma_f32_16x16x32_f16(a2, (BF), cs_, 0,0,0); \
        f4 q3 = __builtin_amdgcn_mfma_f32_16x16x32_f16(a3, (BF), cs_, 0,0,0); \
        _Pragma("unroll")                                                     \
        for (int r = 0; r < 4; ++r) {                                         \
            mx0[r] = fmaxf(mx0[r], q0[r]);                                    \
            mx1[r] = fmaxf(mx1[r], q1[r]);                                    \
            mx2[r] = fmaxf(mx2[r], q2[r]);                                    \
            mx3[r] = fmaxf(mx3[r], q3[r]);                                    \
        }                                                                     \
    }

__global__ __launch_bounds__(256, 4)
void chamfer_pass(const h8* __restrict__ Xpk, const h8* __restrict__ Ypk,
                  const float* __restrict__ x2g, const float* __restrict__ y2g,
                  float* __restrict__ mp, int nh, int tph /* = 128/nh */)
{
    // XCD swizzle (nwg = 512 or 1024, both %8 == 0 -> bijective)
    const int nwg  = gridDim.x;
    const int phys = blockIdx.x;
    const int lg   = (phys & 7) * (nwg >> 3) + (phys >> 3);
    const int xb   = lg & 7;            // 8 row-blocks of 256
    const int rest = lg >> 3;
    const int b    = rest & 31;
    const int z    = rest >> 5;         // 0 .. 2*nh-1
    const int dir  = z / nh;
    const int half = z % nh;

    const int tid = threadIdx.x;
    const int w   = tid >> 6;
    const int l   = tid & 63;
    const int lc  = l & 15;
    const int g   = l >> 4;

    const h8* Ppk = dir ? Ypk : Xpk;
    const h8* Qpk = dir ? Xpk : Ypk;
    const float* qn = dir ? x2g : y2g;

    const int row0 = xb * 256 + w * 64;                   // within batch
    const size_t pt0 = ((size_t)b * NM + row0) >> 4;      // global 16-row tile
    const h8* pa = Ppk + pt0 * 64 + l;
    h8 a0 = pa[0], a1 = pa[64], a2 = pa[128], a3 = pa[192];

    const int mt0 = half * tph;
    const h8*    qb  = Qpk + ((size_t)b * (NM / 16) + mt0) * 64 + l;
    const float* qnb = qn + (size_t)b * NM + mt0 * 16 + lc;

    const float NEGINF = -3.0e38f;
    f4 mx0 = {NEGINF, NEGINF, NEGINF, NEGINF};
    f4 mx1 = mx0, mx2 = mx0, mx3 = mx0;

    // 4-deep register prefetch pipeline (tph is a multiple of 4)
    h8 b0 = qb[0], b1 = qb[64], b2 = qb[128], b3 = qb[192];
    float c0 = qnb[0], c1 = qnb[16], c2 = qnb[32], c3 = qnb[48];

    for (int t = 0; t < tph - 4; t += 4) {
        qb += 4 * 64; qnb += 4 * 16;
        h8 n0 = qb[0], n1 = qb[64], n2 = qb[128], n3 = qb[192];
        float d0 = qnb[0], d1 = qnb[16], d2 = qnb[32], d3 = qnb[48];
        PASS_BODY(b0, c0);
        PASS_BODY(b1, c1);
        PASS_BODY(b2, c2);
        PASS_BODY(b3, c3);
        b0 = n0; b1 = n1; b2 = n2; b3 = n3;
        c0 = d0; c1 = d1; c2 = d2; c3 = d3;
    }
    PASS_BODY(b0, c0);       // tail batch
    PASS_BODY(b1, c1);
    PASS_BODY(b2, c2);
    PASS_BODY(b3, c3);

    // reduce max across the 16 column-lanes
#pragma unroll
    for (int m = 1; m <= 8; m <<= 1) {
#pragma unroll
        for (int r = 0; r < 4; ++r) {
            mx0[r] = fmaxf(mx0[r], __shfl_xor(mx0[r], m));
            mx1[r] = fmaxf(mx1[r], __shfl_xor(mx1[r], m));
            mx2[r] = fmaxf(mx2[r], __shfl_xor(mx2[r], m));
            mx3[r] = fmaxf(mx3[r], __shfl_xor(mx3[r], m));
        }
    }
    if (lc == 0) {   // 4 lanes per wave; rows row0 + i*16 + g*4 .. +3
        float* out = mp + ((size_t)(dir * nh + half) * B_SZ + b) * NM
                        + row0 + (g << 2);
        *(f4*)(out)      = mx0;
        *(f4*)(out + 16) = mx1;
        *(f4*)(out + 32) = mx2;
        *(f4*)(out + 48) = mx3;
    }
}

// ---------------------------------------------------------------------------
// Finalize: d2 = nrm - 2*max(halves), clamp, sqrt, deterministic tree sum.
// Exactly 32768 f4 elements -> grid 128 x 256, one f4 per thread.
// ---------------------------------------------------------------------------
__global__ __launch_bounds__(256)
void finalize1(const float* __restrict__ mp, const float* __restrict__ nrm,
               float* __restrict__ partials, int nh)
{
    const int i   = blockIdx.x * 256 + threadIdx.x;   // f4 index in [0, 32768)
    const int dir = i >> 14;
    const int r4  = i & 16383;
    const f4* n4 = (const f4*)(nrm + dir * 65536);
    const f4* m0 = (const f4*)(mp + (size_t)dir * nh * 65536);
    const f4* m1 = (const f4*)(mp + ((size_t)dir * nh + (nh - 1)) * 65536);
    f4 nv = n4[r4];
    f4 pa = m0[r4];
    f4 pb = m1[r4];   // nh==1: same as pa
    float s = 0.f;
#pragma unroll
    for (int r = 0; r < 4; ++r) {
        float d2 = fmaf(-2.f, fmaxf(pa[r], pb[r]), nv[r]);
        s += sqrtf(fmaxf(d2, 0.f));
    }
    __shared__ float wsum[4];
#pragma unroll
    for (int o = 32; o > 0; o >>= 1) s += __shfl_down(s, o, 64);
    if ((threadIdx.x & 63) == 0) wsum[threadIdx.x >> 6] = s;
    __syncthreads();
    if (threadIdx.x == 0)
        partials[blockIdx.x] = wsum[0] + wsum[1] + wsum[2] + wsum[3];
}

__global__ __launch_bounds__(64)
void finalize2(const float* __restrict__ partials, float* __restrict__ out, float scale)
{
    float s = partials[threadIdx.x] + partials[threadIdx.x + 64];
#pragma unroll
    for (int o = 32; o > 0; o >>= 1) s += __shfl_down(s, o, 64);
    if (threadIdx.x == 0) out[0] = s * scale;
}

extern "C" void kernel_launch(void* const* d_in, const int* in_sizes, int n_in,
                              void* d_out, int out_size, void* d_ws, size_t ws_size,
                              hipStream_t stream) {
    const float* X = (const float*)d_in[0];
    const float* Y = (const float*)d_in[1];

    // ws: mp nh*131072 f + partials 128 f + nrm 131072 f + packed 8.39 MB
    const int nh  = (ws_size >= 10100000u) ? 2 : 1;
    const int tph = 128 / nh;

    float* ws       = (float*)d_ws;
    float* mp       = ws;                              // nh*2*32*2048 floats
    float* partials = mp + (size_t)nh * 131072;        // 128 floats
    float* nrm      = partials + 128;                  // 131072 floats (x2 then y2)
    h8*    Xpk      = (h8*)(nrm + 131072);             // 262144 h8 (4.19 MB)
    h8*    Ypk      = Xpk + 262144;                    // 262144 h8 (4.19 MB)

    dim3 pgrid(1024, 2);
    pack_kernel<<<pgrid, 256, 0, stream>>>(X, Y, Xpk, Ypk, nrm, nrm + 65536);

    // 1D grid: 8 row-blocks x 32 batches x (2*nh) passes, XCD-swizzled inside
    chamfer_pass<<<8 * B_SZ * 2 * nh, 256, 0, stream>>>(Xpk, Ypk, nrm, nrm + 65536,
                                                        mp, nh, tph);

    finalize1<<<128, 256, 0, stream>>>(mp, nrm, partials, nh);
    finalize2<<<1, 64, 0, stream>>>(partials, (float*)d_out, 1.0f / 131072.0f);
}